// Round 1
// baseline (1224.840 us; speedup 1.0000x reference)
//
#include <hip/hip_runtime.h>
#include <math.h>

#define NNODES 50000
#define NEDGES 800000
#define ETOT   (NEDGES + NNODES)
#define HIDC   32
#define NGRAPH 64
#define NCLS   10
#define SLOPE  0.2f

__device__ __forceinline__ float lrelu(float v) { return v > 0.f ? v : SLOPE * v; }

// ---------------- CSR build (by dst), includes self loops ----------------
__global__ void hist_kernel(const int* __restrict__ ei, int* __restrict__ deg) {
  int e = blockIdx.x * 256 + threadIdx.x;
  if (e >= ETOT) return;
  int d = (e < NEDGES) ? ei[NEDGES + e] : (e - NEDGES);
  atomicAdd(&deg[d], 1);
}

__global__ void scan_kernel(const int* __restrict__ deg, int* __restrict__ row_start) {
  __shared__ int wsum[4];
  __shared__ int carry_sh;
  if (threadIdx.x == 0) carry_sh = 0;
  __syncthreads();
  int lane = threadIdx.x & 63, w = threadIdx.x >> 6;
  for (int base = 0; base < NNODES; base += 256) {
    int i = base + threadIdx.x;
    int v = (i < NNODES) ? deg[i] : 0;
    int x = v;
    #pragma unroll
    for (int d = 1; d < 64; d <<= 1) {
      int y = __shfl_up(x, d);
      if (lane >= d) x += y;
    }
    if (lane == 63) wsum[w] = x;
    __syncthreads();
    int woff = 0;
    for (int j = 0; j < w; ++j) woff += wsum[j];
    int inc = x + woff + carry_sh;
    if (i < NNODES) row_start[i] = inc - v;
    __syncthreads();
    if (threadIdx.x == 255) carry_sh = inc;
    __syncthreads();
  }
  if (threadIdx.x == 0) row_start[NNODES] = carry_sh;
}

__global__ void scatter_kernel(const int* __restrict__ ei, const int* __restrict__ row_start,
                               int* __restrict__ cursor, int* __restrict__ col_src) {
  int e = blockIdx.x * 256 + threadIdx.x;
  if (e >= ETOT) return;
  int s, d;
  if (e < NEDGES) { s = ei[e]; d = ei[NEDGES + e]; }
  else { s = d = e - NEDGES; }
  int pos = atomicAdd(&cursor[d], 1);
  col_src[row_start[d] + pos] = s;
}

// ---------------- fp32 tiled GEMM: C[M,Cc] = A[M,K] @ B[K,Cc] (+ bias) ----------------
// 64x64 tile, 256 threads, 4x4 per thread, BK=32. K must be a multiple of 32.
__global__ __launch_bounds__(256)
void gemm_bias(const float* __restrict__ A, const float* __restrict__ B,
               const float* __restrict__ bias, float* __restrict__ Cout,
               int M, int K, int Ccols) {
  __shared__ float As[32][68];  // [k][row], 68 keeps 16B row alignment + bank stagger
  __shared__ float Bs[32][68];  // [k][col]
  int row0 = blockIdx.x * 64, col0 = blockIdx.y * 64;
  int tid = threadIdx.x;
  int tx = tid & 15;   // col group (cols tx*4 .. tx*4+3)
  int ty = tid >> 4;   // row group (rows ty*4 .. ty*4+3)
  float acc[4][4] = {};
  for (int k0 = 0; k0 < K; k0 += 32) {
    #pragma unroll
    for (int i = 0; i < 8; ++i) {
      int idx = tid + i * 256;
      int r = idx >> 5, c = idx & 31;       // A tile: 64 rows x 32 k
      int gr = row0 + r;
      As[c][r] = (gr < M) ? A[(size_t)gr * K + k0 + c] : 0.f;
    }
    #pragma unroll
    for (int i = 0; i < 8; ++i) {
      int idx = tid + i * 256;
      int r = idx >> 6, c = idx & 63;       // B tile: 32 k x 64 cols
      Bs[r][c] = B[(size_t)(k0 + r) * Ccols + col0 + c];
    }
    __syncthreads();
    #pragma unroll
    for (int k = 0; k < 32; ++k) {
      float a4[4], b4[4];
      #pragma unroll
      for (int i = 0; i < 4; ++i) a4[i] = As[k][ty * 4 + i];
      #pragma unroll
      for (int j = 0; j < 4; ++j) b4[j] = Bs[k][tx * 4 + j];
      #pragma unroll
      for (int i = 0; i < 4; ++i)
        #pragma unroll
        for (int j = 0; j < 4; ++j)
          acc[i][j] = fmaf(a4[i], b4[j], acc[i][j]);
    }
    __syncthreads();
  }
  #pragma unroll
  for (int i = 0; i < 4; ++i) {
    int gr = row0 + ty * 4 + i;
    if (gr >= M) continue;
    #pragma unroll
    for (int j = 0; j < 4; ++j) {
      int gc = col0 + tx * 4 + j;
      float bv = bias ? bias[gc] : 0.f;
      Cout[(size_t)gr * Ccols + gc] = acc[i][j] + bv;
    }
  }
}

// ---------------- per-node attention scores: sc_s/sc_d [N,4] ----------------
__global__ __launch_bounds__(256)
void scores_kernel(const float* __restrict__ hproj,
                   const float* __restrict__ a_s, const float* __restrict__ a_d,
                   float* __restrict__ scs, float* __restrict__ scd) {
  int wave = threadIdx.x >> 6, lane = threadIdx.x & 63;
  int node = blockIdx.x * 4 + wave;
  if (node >= NNODES) return;
  float v0 = hproj[(size_t)node * 128 + lane];        // (head lane>>5, ch lane&31)
  float v1 = hproj[(size_t)node * 128 + 64 + lane];   // (head 2+(lane>>5), ch)
  float ps0 = v0 * a_s[lane],      ps1 = v1 * a_s[64 + lane];
  float pd0 = v0 * a_d[lane],      pd1 = v1 * a_d[64 + lane];
  #pragma unroll
  for (int d = 16; d >= 1; d >>= 1) {
    ps0 += __shfl_xor(ps0, d); ps1 += __shfl_xor(ps1, d);
    pd0 += __shfl_xor(pd0, d); pd1 += __shfl_xor(pd1, d);
  }
  if ((lane & 31) == 0) {
    int h0 = lane >> 5;  // 0 or 1
    scs[(size_t)node * 4 + h0]     = ps0;
    scs[(size_t)node * 4 + h0 + 2] = ps1;
    scd[(size_t)node * 4 + h0]     = pd0;
    scd[(size_t)node * 4 + h0 + 2] = pd1;
  }
}

// ---------------- fused GAT edge kernel: softmax + aggregate + mean + bias + ELU ----------------
// one wave per destination node; no atomics, no LDS.
__global__ __launch_bounds__(256)
void gat_edge_kernel(const float* __restrict__ hproj,
                     const float* __restrict__ scs, const float* __restrict__ scd,
                     const int* __restrict__ row_start, const int* __restrict__ col_src,
                     const float* __restrict__ bias, float* __restrict__ hout) {
  int wave = threadIdx.x >> 6, lane = threadIdx.x & 63;
  int node = blockIdx.x * 4 + wave;
  if (node >= NNODES) return;
  int s = row_start[node], e = row_start[node + 1];
  float4 sd = *(const float4*)(scd + (size_t)node * 4);

  // pass 1: per-head segment max over in-edges (lanes = edges)
  float m0 = -INFINITY, m1 = -INFINITY, m2 = -INFINITY, m3 = -INFINITY;
  for (int i = s + lane; i < e; i += 64) {
    int src = col_src[i];
    float4 ss = *(const float4*)(scs + (size_t)src * 4);
    m0 = fmaxf(m0, lrelu(ss.x + sd.x));
    m1 = fmaxf(m1, lrelu(ss.y + sd.y));
    m2 = fmaxf(m2, lrelu(ss.z + sd.z));
    m3 = fmaxf(m3, lrelu(ss.w + sd.w));
  }
  #pragma unroll
  for (int d = 32; d >= 1; d >>= 1) {
    m0 = fmaxf(m0, __shfl_xor(m0, d));
    m1 = fmaxf(m1, __shfl_xor(m1, d));
    m2 = fmaxf(m2, __shfl_xor(m2, d));
    m3 = fmaxf(m3, __shfl_xor(m3, d));
  }

  // pass 2 (chunked): compute alphas (lanes = edges), then channel-parallel
  // unnormalized accumulation (lanes = 2 x (head, channel)); normalize at end.
  int hA = lane >> 5;          // head for acc0 (acc1 is head hA+2), channel = lane&31
  float den0 = 0, den1 = 0, den2 = 0, den3 = 0;
  float acc0 = 0, acc1 = 0;
  for (int base = s; base < e; base += 64) {
    int i = base + lane;
    int cnt = min(64, e - base);
    int srcReg = 0;
    float a0 = 0, a1 = 0, a2 = 0, a3 = 0;
    if (i < e) {
      srcReg = col_src[i];
      float4 ss = *(const float4*)(scs + (size_t)srcReg * 4);
      a0 = __expf(lrelu(ss.x + sd.x) - m0);
      a1 = __expf(lrelu(ss.y + sd.y) - m1);
      a2 = __expf(lrelu(ss.z + sd.z) - m2);
      a3 = __expf(lrelu(ss.w + sd.w) - m3);
      den0 += a0; den1 += a1; den2 += a2; den3 += a3;
    }
    for (int j = 0; j < cnt; ++j) {
      int src  = __shfl(srcReg, j);
      float t0 = __shfl(a0, j), t1 = __shfl(a1, j);
      float t2 = __shfl(a2, j), t3 = __shfl(a3, j);
      float alA = hA ? t1 : t0;
      float alB = hA ? t3 : t2;
      const float* hp = hproj + (size_t)src * 128;
      acc0 = fmaf(alA, hp[lane],      acc0);   // head hA,   channel lane&31
      acc1 = fmaf(alB, hp[64 + lane], acc1);   // head hA+2, channel lane&31
    }
  }
  #pragma unroll
  for (int d = 32; d >= 1; d >>= 1) {
    den0 += __shfl_xor(den0, d);
    den1 += __shfl_xor(den1, d);
    den2 += __shfl_xor(den2, d);
    den3 += __shfl_xor(den3, d);
  }
  float rdenA = 1.f / fmaxf(hA ? den1 : den0, 1e-16f);
  float rdenB = 1.f / fmaxf(hA ? den3 : den2, 1e-16f);
  float sum = acc0 * rdenA + acc1 * rdenB;   // heads {hA, hA+2} for channel lane&31
  sum += __shfl_xor(sum, 32);                // add heads {1-hA, 3-hA}
  if (lane < 32) {
    float v = sum * 0.25f + bias[lane];      // head mean + bias
    hout[(size_t)node * 32 + lane] = v > 0.f ? v : expm1f(v);  // ELU
  }
}

// ---------------- global mean pool + classifier ----------------
__global__ void pool_kernel(const float* __restrict__ h, const int* __restrict__ batch,
                            float* __restrict__ pooled, float* __restrict__ cnt) {
  int idx = blockIdx.x * 256 + threadIdx.x;
  if (idx >= NNODES * HIDC) return;
  int node = idx >> 5, c = idx & 31;
  int b = batch[node];
  atomicAdd(&pooled[b * HIDC + c], h[idx]);
  if (c == 0) atomicAdd(&cnt[b], 1.f);
}

__global__ void final_kernel(const float* __restrict__ pooled, const float* __restrict__ cnt,
                             const float* __restrict__ w, const float* __restrict__ b,
                             float* __restrict__ out) {
  int t = threadIdx.x;
  if (t >= NGRAPH * NCLS) return;
  int g = t / NCLS, j = t - g * NCLS;
  float inv = 1.f / fmaxf(cnt[g], 1.f);
  float acc = 0.f;
  #pragma unroll
  for (int c = 0; c < HIDC; ++c)
    acc = fmaf(pooled[g * HIDC + c], w[c * NCLS + j], acc);
  out[t] = acc * inv + b[j];
}

extern "C" void kernel_launch(void* const* d_in, const int* in_sizes, int n_in,
                              void* d_out, int out_size, void* d_ws, size_t ws_size,
                              hipStream_t stream) {
  const float* x      = (const float*)d_in[0];
  const int*   ei     = (const int*)d_in[1];
  const int*   batch  = (const int*)d_in[2];
  const float* enc1_w = (const float*)d_in[3];
  const float* enc1_b = (const float*)d_in[4];
  const float* enc2_w = (const float*)d_in[5];
  const float* enc2_b = (const float*)d_in[6];
  const float* lin1_w = (const float*)d_in[7];
  const float* lin1_b = (const float*)d_in[8];
  const float* gw[4]  = {(const float*)d_in[9],  (const float*)d_in[13], (const float*)d_in[17], (const float*)d_in[21]};
  const float* gas[4] = {(const float*)d_in[10], (const float*)d_in[14], (const float*)d_in[18], (const float*)d_in[22]};
  const float* gad[4] = {(const float*)d_in[11], (const float*)d_in[15], (const float*)d_in[19], (const float*)d_in[23]};
  const float* gb[4]  = {(const float*)d_in[12], (const float*)d_in[16], (const float*)d_in[20], (const float*)d_in[24]};
  float* out = (float*)d_out;

  // workspace carve (~89 MB)
  float* fws    = (float*)d_ws;
  float* hproj  = fws;                                  // N*128 (also enc1 out)
  float* hbig   = hproj  + (size_t)NNODES * 128;        // N*256 (enc2 out)
  float* hsmall = hbig   + (size_t)NNODES * 256;        // N*32  (layer outputs)
  float* scs    = hsmall + (size_t)NNODES * 32;         // N*4
  float* scd    = scs    + (size_t)NNODES * 4;          // N*4
  float* pooled = scd    + (size_t)NNODES * 4;          // 64*32
  float* cnt    = pooled + NGRAPH * HIDC;               // 64
  int*   deg    = (int*)(cnt + NGRAPH);                 // N (reused as cursor)
  int*   row_start = deg + NNODES;                      // N+1
  int*   col_src   = row_start + NNODES + 1;            // ETOT

  // --- CSR build ---
  hipMemsetAsync(deg, 0, NNODES * sizeof(int), stream);
  hist_kernel<<<(ETOT + 255) / 256, 256, 0, stream>>>(ei, deg);
  scan_kernel<<<1, 256, 0, stream>>>(deg, row_start);
  hipMemsetAsync(deg, 0, NNODES * sizeof(int), stream);
  scatter_kernel<<<(ETOT + 255) / 256, 256, 0, stream>>>(ei, row_start, deg, col_src);

  dim3 g128((NNODES + 63) / 64, 2), g256((NNODES + 63) / 64, 4);

  // --- encoders ---
  gemm_bias<<<g128, 256, 0, stream>>>(x,     enc1_w, enc1_b, hproj, NNODES, 128, 128);
  gemm_bias<<<g256, 256, 0, stream>>>(hproj, enc2_w, enc2_b, hbig,  NNODES, 128, 256);

  // --- 4 GAT layers ---
  const float* cur = hbig; int curK = 256;
  for (int L = 0; L < 4; ++L) {
    gemm_bias<<<g128, 256, 0, stream>>>(cur, gw[L], nullptr, hproj, NNODES, curK, 128);
    scores_kernel<<<(NNODES + 3) / 4, 256, 0, stream>>>(hproj, gas[L], gad[L], scs, scd);
    gat_edge_kernel<<<(NNODES + 3) / 4, 256, 0, stream>>>(hproj, scs, scd, row_start, col_src, gb[L], hsmall);
    cur = hsmall; curK = 32;
  }

  // --- pooling + classifier ---
  hipMemsetAsync(pooled, 0, (NGRAPH * HIDC + NGRAPH) * sizeof(float), stream);
  pool_kernel<<<(NNODES * HIDC + 255) / 256, 256, 0, stream>>>(hsmall, batch, pooled, cnt);
  final_kernel<<<1, 640, 0, stream>>>(pooled, cnt, lin1_w, lin1_b, out);
}

// Round 2
// 856.924 us; speedup vs baseline: 1.4293x; 1.4293x over previous
//
#include <hip/hip_runtime.h>
#include <math.h>

#define NNODES 50000
#define NEDGES 800000
#define ETOT   (NEDGES + NNODES)
#define HIDC   32
#define NGRAPH 64
#define NCLS   10
#define SLOPE  0.2f

__device__ __forceinline__ float lrelu(float v) { return v > 0.f ? v : SLOPE * v; }

// ---------------- CSR build (by dst), includes self loops ----------------
__global__ void hist_kernel(const int* __restrict__ ei, int* __restrict__ deg) {
  int e = blockIdx.x * 256 + threadIdx.x;
  if (e >= ETOT) return;
  int d = (e < NEDGES) ? ei[NEDGES + e] : (e - NEDGES);
  atomicAdd(&deg[d], 1);
}

__global__ void scan_kernel(const int* __restrict__ deg, int* __restrict__ row_start) {
  __shared__ int wsum[4];
  __shared__ int carry_sh;
  if (threadIdx.x == 0) carry_sh = 0;
  __syncthreads();
  int lane = threadIdx.x & 63, w = threadIdx.x >> 6;
  for (int base = 0; base < NNODES; base += 256) {
    int i = base + threadIdx.x;
    int v = (i < NNODES) ? deg[i] : 0;
    int x = v;
    #pragma unroll
    for (int d = 1; d < 64; d <<= 1) {
      int y = __shfl_up(x, d);
      if (lane >= d) x += y;
    }
    if (lane == 63) wsum[w] = x;
    __syncthreads();
    int woff = 0;
    for (int j = 0; j < w; ++j) woff += wsum[j];
    int inc = x + woff + carry_sh;
    if (i < NNODES) row_start[i] = inc - v;
    __syncthreads();
    if (threadIdx.x == 255) carry_sh = inc;
    __syncthreads();
  }
  if (threadIdx.x == 0) row_start[NNODES] = carry_sh;
}

__global__ void scatter_kernel(const int* __restrict__ ei, const int* __restrict__ row_start,
                               int* __restrict__ cursor, int* __restrict__ col_src) {
  int e = blockIdx.x * 256 + threadIdx.x;
  if (e >= ETOT) return;
  int s, d;
  if (e < NEDGES) { s = ei[e]; d = ei[NEDGES + e]; }
  else { s = d = e - NEDGES; }
  int pos = atomicAdd(&cursor[d], 1);
  col_src[row_start[d] + pos] = s;
}

// ---------------- fp32 tiled GEMM: C[M,Cc] = A[M,K] @ B[K,Cc] (+ bias) ----------------
__global__ __launch_bounds__(256)
void gemm_bias(const float* __restrict__ A, const float* __restrict__ B,
               const float* __restrict__ bias, float* __restrict__ Cout,
               int M, int K, int Ccols) {
  __shared__ float As[32][68];
  __shared__ float Bs[32][68];
  int row0 = blockIdx.x * 64, col0 = blockIdx.y * 64;
  int tid = threadIdx.x;
  int tx = tid & 15;
  int ty = tid >> 4;
  float acc[4][4] = {};
  for (int k0 = 0; k0 < K; k0 += 32) {
    #pragma unroll
    for (int i = 0; i < 8; ++i) {
      int idx = tid + i * 256;
      int r = idx >> 5, c = idx & 31;
      int gr = row0 + r;
      As[c][r] = (gr < M) ? A[(size_t)gr * K + k0 + c] : 0.f;
    }
    #pragma unroll
    for (int i = 0; i < 8; ++i) {
      int idx = tid + i * 256;
      int r = idx >> 6, c = idx & 63;
      Bs[r][c] = B[(size_t)(k0 + r) * Ccols + col0 + c];
    }
    __syncthreads();
    #pragma unroll
    for (int k = 0; k < 32; ++k) {
      float a4[4], b4[4];
      #pragma unroll
      for (int i = 0; i < 4; ++i) a4[i] = As[k][ty * 4 + i];
      #pragma unroll
      for (int j = 0; j < 4; ++j) b4[j] = Bs[k][tx * 4 + j];
      #pragma unroll
      for (int i = 0; i < 4; ++i)
        #pragma unroll
        for (int j = 0; j < 4; ++j)
          acc[i][j] = fmaf(a4[i], b4[j], acc[i][j]);
    }
    __syncthreads();
  }
  #pragma unroll
  for (int i = 0; i < 4; ++i) {
    int gr = row0 + ty * 4 + i;
    if (gr >= M) continue;
    #pragma unroll
    for (int j = 0; j < 4; ++j) {
      int gc = col0 + tx * 4 + j;
      float bv = bias ? bias[gc] : 0.f;
      Cout[(size_t)gr * Ccols + gc] = acc[i][j] + bv;
    }
  }
}

// ---------------- per-node attention scores: sc_s/sc_d [N,4] ----------------
__global__ __launch_bounds__(256)
void scores_kernel(const float* __restrict__ hproj,
                   const float* __restrict__ a_s, const float* __restrict__ a_d,
                   float* __restrict__ scs, float* __restrict__ scd) {
  int wave = threadIdx.x >> 6, lane = threadIdx.x & 63;
  int node = blockIdx.x * 4 + wave;
  if (node >= NNODES) return;
  float v0 = hproj[(size_t)node * 128 + lane];
  float v1 = hproj[(size_t)node * 128 + 64 + lane];
  float ps0 = v0 * a_s[lane],      ps1 = v1 * a_s[64 + lane];
  float pd0 = v0 * a_d[lane],      pd1 = v1 * a_d[64 + lane];
  #pragma unroll
  for (int d = 16; d >= 1; d >>= 1) {
    ps0 += __shfl_xor(ps0, d); ps1 += __shfl_xor(ps1, d);
    pd0 += __shfl_xor(pd0, d); pd1 += __shfl_xor(pd1, d);
  }
  if ((lane & 31) == 0) {
    int h0 = lane >> 5;
    scs[(size_t)node * 4 + h0]     = ps0;
    scs[(size_t)node * 4 + h0 + 2] = ps1;
    scd[(size_t)node * 4 + h0]     = pd0;
    scd[(size_t)node * 4 + h0 + 2] = pd1;
  }
}

// ---------------- fused GAT edge kernel ----------------
__global__ __launch_bounds__(256)
void gat_edge_kernel(const float* __restrict__ hproj,
                     const float* __restrict__ scs, const float* __restrict__ scd,
                     const int* __restrict__ row_start, const int* __restrict__ col_src,
                     const float* __restrict__ bias, float* __restrict__ hout) {
  int wave = threadIdx.x >> 6, lane = threadIdx.x & 63;
  int node = blockIdx.x * 4 + wave;
  if (node >= NNODES) return;
  int s = row_start[node], e = row_start[node + 1];
  float4 sd = *(const float4*)(scd + (size_t)node * 4);

  float m0 = -INFINITY, m1 = -INFINITY, m2 = -INFINITY, m3 = -INFINITY;
  for (int i = s + lane; i < e; i += 64) {
    int src = col_src[i];
    float4 ss = *(const float4*)(scs + (size_t)src * 4);
    m0 = fmaxf(m0, lrelu(ss.x + sd.x));
    m1 = fmaxf(m1, lrelu(ss.y + sd.y));
    m2 = fmaxf(m2, lrelu(ss.z + sd.z));
    m3 = fmaxf(m3, lrelu(ss.w + sd.w));
  }
  #pragma unroll
  for (int d = 32; d >= 1; d >>= 1) {
    m0 = fmaxf(m0, __shfl_xor(m0, d));
    m1 = fmaxf(m1, __shfl_xor(m1, d));
    m2 = fmaxf(m2, __shfl_xor(m2, d));
    m3 = fmaxf(m3, __shfl_xor(m3, d));
  }

  int hA = lane >> 5;
  float den0 = 0, den1 = 0, den2 = 0, den3 = 0;
  float acc0 = 0, acc1 = 0;
  for (int base = s; base < e; base += 64) {
    int i = base + lane;
    int cnt = min(64, e - base);
    int srcReg = 0;
    float a0 = 0, a1 = 0, a2 = 0, a3 = 0;
    if (i < e) {
      srcReg = col_src[i];
      float4 ss = *(const float4*)(scs + (size_t)srcReg * 4);
      a0 = __expf(lrelu(ss.x + sd.x) - m0);
      a1 = __expf(lrelu(ss.y + sd.y) - m1);
      a2 = __expf(lrelu(ss.z + sd.z) - m2);
      a3 = __expf(lrelu(ss.w + sd.w) - m3);
      den0 += a0; den1 += a1; den2 += a2; den3 += a3;
    }
    for (int j = 0; j < cnt; ++j) {
      int src  = __shfl(srcReg, j);
      float t0 = __shfl(a0, j), t1 = __shfl(a1, j);
      float t2 = __shfl(a2, j), t3 = __shfl(a3, j);
      float alA = hA ? t1 : t0;
      float alB = hA ? t3 : t2;
      const float* hp = hproj + (size_t)src * 128;
      acc0 = fmaf(alA, hp[lane],      acc0);
      acc1 = fmaf(alB, hp[64 + lane], acc1);
    }
  }
  #pragma unroll
  for (int d = 32; d >= 1; d >>= 1) {
    den0 += __shfl_xor(den0, d);
    den1 += __shfl_xor(den1, d);
    den2 += __shfl_xor(den2, d);
    den3 += __shfl_xor(den3, d);
  }
  float rdenA = 1.f / fmaxf(hA ? den1 : den0, 1e-16f);
  float rdenB = 1.f / fmaxf(hA ? den3 : den2, 1e-16f);
  float sum = acc0 * rdenA + acc1 * rdenB;
  sum += __shfl_xor(sum, 32);
  if (lane < 32) {
    float v = sum * 0.25f + bias[lane];
    hout[(size_t)node * 32 + lane] = v > 0.f ? v : expm1f(v);
  }
}

// ---------------- hierarchical global mean pool ----------------
// Each block accumulates a contiguous node chunk into LDS (batch is sorted,
// so a chunk spans ~1-3 graphs), then flushes only the spanned rows with one
// global atomic per (graph,channel). Global atomics: 1.65M -> ~15K.
#define POOL_BLOCKS 128
__global__ __launch_bounds__(256)
void pool_kernel(const float* __restrict__ h, const int* __restrict__ batch,
                 float* __restrict__ pooled, float* __restrict__ cnt) {
  __shared__ float acc[NGRAPH][HIDC];   // 8 KB
  __shared__ float ccnt[NGRAPH];
  int tid = threadIdx.x;
  const int chunk = (NNODES + POOL_BLOCKS - 1) / POOL_BLOCKS;
  int n0 = blockIdx.x * chunk;
  int n1 = min(n0 + chunk, NNODES);
  if (n0 >= NNODES) return;
  int g0 = batch[n0], g1 = batch[n1 - 1];
  int rows = g1 - g0 + 1;
  for (int idx = tid; idx < rows * HIDC; idx += 256)
    acc[g0 + (idx >> 5)][idx & 31] = 0.f;
  for (int g = tid; g < rows; g += 256) ccnt[g0 + g] = 0.f;
  __syncthreads();
  int c = tid & 31;
  for (int node = n0 + (tid >> 5); node < n1; node += 8) {
    int g = batch[node];
    atomicAdd(&acc[g][c], h[(size_t)node * HIDC + c]);
    if (c == 0) atomicAdd(&ccnt[g], 1.f);
  }
  __syncthreads();
  for (int idx = tid; idx < rows * HIDC; idx += 256) {
    int g = g0 + (idx >> 5), cc = idx & 31;
    atomicAdd(&pooled[g * HIDC + cc], acc[g][cc]);
  }
  for (int g = tid; g < rows; g += 256) atomicAdd(&cnt[g0 + g], ccnt[g0 + g]);
}

__global__ void final_kernel(const float* __restrict__ pooled, const float* __restrict__ cnt,
                             const float* __restrict__ w, const float* __restrict__ b,
                             float* __restrict__ out) {
  int t = threadIdx.x;
  if (t >= NGRAPH * NCLS) return;
  int g = t / NCLS, j = t - g * NCLS;
  float inv = 1.f / fmaxf(cnt[g], 1.f);
  float acc = 0.f;
  #pragma unroll
  for (int c = 0; c < HIDC; ++c)
    acc = fmaf(pooled[g * HIDC + c], w[c * NCLS + j], acc);
  out[t] = acc * inv + b[j];
}

extern "C" void kernel_launch(void* const* d_in, const int* in_sizes, int n_in,
                              void* d_out, int out_size, void* d_ws, size_t ws_size,
                              hipStream_t stream) {
  const float* x      = (const float*)d_in[0];
  const int*   ei     = (const int*)d_in[1];
  const int*   batch  = (const int*)d_in[2];
  const float* enc1_w = (const float*)d_in[3];
  const float* enc1_b = (const float*)d_in[4];
  const float* enc2_w = (const float*)d_in[5];
  const float* enc2_b = (const float*)d_in[6];
  const float* lin1_w = (const float*)d_in[7];
  const float* lin1_b = (const float*)d_in[8];
  const float* gw[4]  = {(const float*)d_in[9],  (const float*)d_in[13], (const float*)d_in[17], (const float*)d_in[21]};
  const float* gas[4] = {(const float*)d_in[10], (const float*)d_in[14], (const float*)d_in[18], (const float*)d_in[22]};
  const float* gad[4] = {(const float*)d_in[11], (const float*)d_in[15], (const float*)d_in[19], (const float*)d_in[23]};
  const float* gb[4]  = {(const float*)d_in[12], (const float*)d_in[16], (const float*)d_in[20], (const float*)d_in[24]};
  float* out = (float*)d_out;

  float* fws    = (float*)d_ws;
  float* hproj  = fws;
  float* hbig   = hproj  + (size_t)NNODES * 128;
  float* hsmall = hbig   + (size_t)NNODES * 256;
  float* scs    = hsmall + (size_t)NNODES * 32;
  float* scd    = scs    + (size_t)NNODES * 4;
  float* pooled = scd    + (size_t)NNODES * 4;
  float* cnt    = pooled + NGRAPH * HIDC;
  int*   deg    = (int*)(cnt + NGRAPH);
  int*   row_start = deg + NNODES;
  int*   col_src   = row_start + NNODES + 1;

  hipMemsetAsync(deg, 0, NNODES * sizeof(int), stream);
  hist_kernel<<<(ETOT + 255) / 256, 256, 0, stream>>>(ei, deg);
  scan_kernel<<<1, 256, 0, stream>>>(deg, row_start);
  hipMemsetAsync(deg, 0, NNODES * sizeof(int), stream);
  scatter_kernel<<<(ETOT + 255) / 256, 256, 0, stream>>>(ei, row_start, deg, col_src);

  dim3 g128((NNODES + 63) / 64, 2), g256((NNODES + 63) / 64, 4);

  gemm_bias<<<g128, 256, 0, stream>>>(x,     enc1_w, enc1_b, hproj, NNODES, 128, 128);
  gemm_bias<<<g256, 256, 0, stream>>>(hproj, enc2_w, enc2_b, hbig,  NNODES, 128, 256);

  const float* cur = hbig; int curK = 256;
  for (int L = 0; L < 4; ++L) {
    gemm_bias<<<g128, 256, 0, stream>>>(cur, gw[L], nullptr, hproj, NNODES, curK, 128);
    scores_kernel<<<(NNODES + 3) / 4, 256, 0, stream>>>(hproj, gas[L], gad[L], scs, scd);
    gat_edge_kernel<<<(NNODES + 3) / 4, 256, 0, stream>>>(hproj, scs, scd, row_start, col_src, gb[L], hsmall);
    cur = hsmall; curK = 32;
  }

  hipMemsetAsync(pooled, 0, (NGRAPH * HIDC + NGRAPH) * sizeof(float), stream);
  pool_kernel<<<POOL_BLOCKS, 256, 0, stream>>>(hsmall, batch, pooled, cnt);
  final_kernel<<<1, 640, 0, stream>>>(pooled, cnt, lin1_w, lin1_b, out);
}

// Round 3
// 726.036 us; speedup vs baseline: 1.6870x; 1.1803x over previous
//
#include <hip/hip_runtime.h>
#include <math.h>

#define NNODES 50000
#define NEDGES 800000
#define ETOT   (NEDGES + NNODES)
#define HIDC   32
#define NGRAPH 64
#define NCLS   10
#define SLOPE  0.2f
#define SCAN_BLOCKS ((NNODES + 255) / 256)   // 196

__device__ __forceinline__ float lrelu(float v) { return v > 0.f ? v : SLOPE * v; }

// ---------------- CSR build (by dst), includes self loops ----------------
__global__ void hist_kernel(const int* __restrict__ ei, int* __restrict__ deg) {
  int e = blockIdx.x * 256 + threadIdx.x;
  if (e >= ETOT) return;
  int d = (e < NEDGES) ? ei[NEDGES + e] : (e - NEDGES);
  atomicAdd(&deg[d], 1);
}

// phase 1: per-block inclusive scan -> block-local exclusive + block sum
__global__ __launch_bounds__(256)
void scan_block_kernel(const int* __restrict__ deg, int* __restrict__ row_start,
                       int* __restrict__ bsum) {
  __shared__ int wsum[4];
  int i = blockIdx.x * 256 + threadIdx.x;
  int v = (i < NNODES) ? deg[i] : 0;
  int lane = threadIdx.x & 63, w = threadIdx.x >> 6;
  int x = v;
  #pragma unroll
  for (int d = 1; d < 64; d <<= 1) {
    int y = __shfl_up(x, d);
    if (lane >= d) x += y;
  }
  if (lane == 63) wsum[w] = x;
  __syncthreads();
  int woff = 0;
  #pragma unroll
  for (int j = 0; j < 4; ++j) if (j < w) woff += wsum[j];
  int incl = x + woff;
  if (i < NNODES) row_start[i] = incl - v;
  if (threadIdx.x == 255) bsum[blockIdx.x] = incl;
}

// phase 2: single-block exclusive scan of the 196 block sums
__global__ __launch_bounds__(256)
void scan_sums_kernel(const int* __restrict__ bsum, int* __restrict__ boff) {
  __shared__ int wsum[4];
  int tid = threadIdx.x;
  int v = (tid < SCAN_BLOCKS) ? bsum[tid] : 0;
  int lane = tid & 63, w = tid >> 6;
  int x = v;
  #pragma unroll
  for (int d = 1; d < 64; d <<= 1) {
    int y = __shfl_up(x, d);
    if (lane >= d) x += y;
  }
  if (lane == 63) wsum[w] = x;
  __syncthreads();
  int woff = 0;
  #pragma unroll
  for (int j = 0; j < 4; ++j) if (j < w) woff += wsum[j];
  if (tid < SCAN_BLOCKS) boff[tid] = (x + woff) - v;
}

// phase 3: add block offsets
__global__ __launch_bounds__(256)
void scan_add_kernel(const int* __restrict__ boff, int* __restrict__ row_start) {
  int i = blockIdx.x * 256 + threadIdx.x;
  if (i < NNODES) row_start[i] += boff[blockIdx.x];
  if (i == 0) row_start[NNODES] = ETOT;   // total is statically known
}

__global__ void scatter_kernel(const int* __restrict__ ei, const int* __restrict__ row_start,
                               int* __restrict__ cursor, int* __restrict__ col_src) {
  int e = blockIdx.x * 256 + threadIdx.x;
  if (e >= ETOT) return;
  int s, d;
  if (e < NEDGES) { s = ei[e]; d = ei[NEDGES + e]; }
  else { s = d = e - NEDGES; }
  int pos = atomicAdd(&cursor[d], 1);
  col_src[row_start[d] + pos] = s;
}

// ---------------- fp32 tiled GEMM: C[M,Cc] = A[M,K] @ B[K,Cc] (+ bias) ----------------
__global__ __launch_bounds__(256)
void gemm_bias(const float* __restrict__ A, const float* __restrict__ B,
               const float* __restrict__ bias, float* __restrict__ Cout,
               int M, int K, int Ccols) {
  __shared__ float As[32][68];
  __shared__ float Bs[32][68];
  int row0 = blockIdx.x * 64, col0 = blockIdx.y * 64;
  int tid = threadIdx.x;
  int tx = tid & 15;
  int ty = tid >> 4;
  float acc[4][4] = {};
  for (int k0 = 0; k0 < K; k0 += 32) {
    #pragma unroll
    for (int i = 0; i < 8; ++i) {
      int idx = tid + i * 256;
      int r = idx >> 5, c = idx & 31;
      int gr = row0 + r;
      As[c][r] = (gr < M) ? A[(size_t)gr * K + k0 + c] : 0.f;
    }
    #pragma unroll
    for (int i = 0; i < 8; ++i) {
      int idx = tid + i * 256;
      int r = idx >> 6, c = idx & 63;
      Bs[r][c] = B[(size_t)(k0 + r) * Ccols + col0 + c];
    }
    __syncthreads();
    #pragma unroll
    for (int k = 0; k < 32; ++k) {
      float a4[4], b4[4];
      #pragma unroll
      for (int i = 0; i < 4; ++i) a4[i] = As[k][ty * 4 + i];
      #pragma unroll
      for (int j = 0; j < 4; ++j) b4[j] = Bs[k][tx * 4 + j];
      #pragma unroll
      for (int i = 0; i < 4; ++i)
        #pragma unroll
        for (int j = 0; j < 4; ++j)
          acc[i][j] = fmaf(a4[i], b4[j], acc[i][j]);
    }
    __syncthreads();
  }
  #pragma unroll
  for (int i = 0; i < 4; ++i) {
    int gr = row0 + ty * 4 + i;
    if (gr >= M) continue;
    #pragma unroll
    for (int j = 0; j < 4; ++j) {
      int gc = col0 + tx * 4 + j;
      float bv = bias ? bias[gc] : 0.f;
      Cout[(size_t)gr * Ccols + gc] = acc[i][j] + bv;
    }
  }
}

// ---------------- per-node attention scores: sc_s/sc_d [N,4] ----------------
__global__ __launch_bounds__(256)
void scores_kernel(const float* __restrict__ hproj,
                   const float* __restrict__ a_s, const float* __restrict__ a_d,
                   float* __restrict__ scs, float* __restrict__ scd) {
  int wave = threadIdx.x >> 6, lane = threadIdx.x & 63;
  int node = blockIdx.x * 4 + wave;
  if (node >= NNODES) return;
  float v0 = hproj[(size_t)node * 128 + lane];
  float v1 = hproj[(size_t)node * 128 + 64 + lane];
  float ps0 = v0 * a_s[lane],      ps1 = v1 * a_s[64 + lane];
  float pd0 = v0 * a_d[lane],      pd1 = v1 * a_d[64 + lane];
  #pragma unroll
  for (int d = 16; d >= 1; d >>= 1) {
    ps0 += __shfl_xor(ps0, d); ps1 += __shfl_xor(ps1, d);
    pd0 += __shfl_xor(pd0, d); pd1 += __shfl_xor(pd1, d);
  }
  if ((lane & 31) == 0) {
    int h0 = lane >> 5;
    scs[(size_t)node * 4 + h0]     = ps0;
    scs[(size_t)node * 4 + h0 + 2] = ps1;
    scd[(size_t)node * 4 + h0]     = pd0;
    scd[(size_t)node * 4 + h0 + 2] = pd1;
  }
}

// ---------------- fused GAT edge kernel ----------------
__global__ __launch_bounds__(256)
void gat_edge_kernel(const float* __restrict__ hproj,
                     const float* __restrict__ scs, const float* __restrict__ scd,
                     const int* __restrict__ row_start, const int* __restrict__ col_src,
                     const float* __restrict__ bias, float* __restrict__ hout) {
  int wave = threadIdx.x >> 6, lane = threadIdx.x & 63;
  int node = blockIdx.x * 4 + wave;
  if (node >= NNODES) return;
  int s = row_start[node], e = row_start[node + 1];
  float4 sd = *(const float4*)(scd + (size_t)node * 4);

  float m0 = -INFINITY, m1 = -INFINITY, m2 = -INFINITY, m3 = -INFINITY;
  for (int i = s + lane; i < e; i += 64) {
    int src = col_src[i];
    float4 ss = *(const float4*)(scs + (size_t)src * 4);
    m0 = fmaxf(m0, lrelu(ss.x + sd.x));
    m1 = fmaxf(m1, lrelu(ss.y + sd.y));
    m2 = fmaxf(m2, lrelu(ss.z + sd.z));
    m3 = fmaxf(m3, lrelu(ss.w + sd.w));
  }
  #pragma unroll
  for (int d = 32; d >= 1; d >>= 1) {
    m0 = fmaxf(m0, __shfl_xor(m0, d));
    m1 = fmaxf(m1, __shfl_xor(m1, d));
    m2 = fmaxf(m2, __shfl_xor(m2, d));
    m3 = fmaxf(m3, __shfl_xor(m3, d));
  }

  int hA = lane >> 5;
  float den0 = 0, den1 = 0, den2 = 0, den3 = 0;
  float acc0 = 0, acc1 = 0;
  for (int base = s; base < e; base += 64) {
    int i = base + lane;
    int cnt = min(64, e - base);
    int srcReg = 0;
    float a0 = 0, a1 = 0, a2 = 0, a3 = 0;
    if (i < e) {
      srcReg = col_src[i];
      float4 ss = *(const float4*)(scs + (size_t)srcReg * 4);
      a0 = __expf(lrelu(ss.x + sd.x) - m0);
      a1 = __expf(lrelu(ss.y + sd.y) - m1);
      a2 = __expf(lrelu(ss.z + sd.z) - m2);
      a3 = __expf(lrelu(ss.w + sd.w) - m3);
      den0 += a0; den1 += a1; den2 += a2; den3 += a3;
    }
    for (int j = 0; j < cnt; ++j) {
      int src  = __shfl(srcReg, j);
      float t0 = __shfl(a0, j), t1 = __shfl(a1, j);
      float t2 = __shfl(a2, j), t3 = __shfl(a3, j);
      float alA = hA ? t1 : t0;
      float alB = hA ? t3 : t2;
      const float* hp = hproj + (size_t)src * 128;
      acc0 = fmaf(alA, hp[lane],      acc0);
      acc1 = fmaf(alB, hp[64 + lane], acc1);
    }
  }
  #pragma unroll
  for (int d = 32; d >= 1; d >>= 1) {
    den0 += __shfl_xor(den0, d);
    den1 += __shfl_xor(den1, d);
    den2 += __shfl_xor(den2, d);
    den3 += __shfl_xor(den3, d);
  }
  float rdenA = 1.f / fmaxf(hA ? den1 : den0, 1e-16f);
  float rdenB = 1.f / fmaxf(hA ? den3 : den2, 1e-16f);
  float sum = acc0 * rdenA + acc1 * rdenB;
  sum += __shfl_xor(sum, 32);
  if (lane < 32) {
    float v = sum * 0.25f + bias[lane];
    hout[(size_t)node * 32 + lane] = v > 0.f ? v : expm1f(v);
  }
}

// ---------------- hierarchical global mean pool ----------------
#define POOL_BLOCKS 128
__global__ __launch_bounds__(256)
void pool_kernel(const float* __restrict__ h, const int* __restrict__ batch,
                 float* __restrict__ pooled, float* __restrict__ cnt) {
  __shared__ float acc[NGRAPH][HIDC];
  __shared__ float ccnt[NGRAPH];
  int tid = threadIdx.x;
  const int chunk = (NNODES + POOL_BLOCKS - 1) / POOL_BLOCKS;
  int n0 = blockIdx.x * chunk;
  int n1 = min(n0 + chunk, NNODES);
  if (n0 >= NNODES) return;
  int g0 = batch[n0], g1 = batch[n1 - 1];
  int rows = g1 - g0 + 1;
  for (int idx = tid; idx < rows * HIDC; idx += 256)
    acc[g0 + (idx >> 5)][idx & 31] = 0.f;
  for (int g = tid; g < rows; g += 256) ccnt[g0 + g] = 0.f;
  __syncthreads();
  int c = tid & 31;
  for (int node = n0 + (tid >> 5); node < n1; node += 8) {
    int g = batch[node];
    atomicAdd(&acc[g][c], h[(size_t)node * HIDC + c]);
    if (c == 0) atomicAdd(&ccnt[g], 1.f);
  }
  __syncthreads();
  for (int idx = tid; idx < rows * HIDC; idx += 256) {
    int g = g0 + (idx >> 5), cc = idx & 31;
    atomicAdd(&pooled[g * HIDC + cc], acc[g][cc]);
  }
  for (int g = tid; g < rows; g += 256) atomicAdd(&cnt[g0 + g], ccnt[g0 + g]);
}

__global__ void final_kernel(const float* __restrict__ pooled, const float* __restrict__ cnt,
                             const float* __restrict__ w, const float* __restrict__ b,
                             float* __restrict__ out) {
  int t = threadIdx.x;
  if (t >= NGRAPH * NCLS) return;
  int g = t / NCLS, j = t - g * NCLS;
  float inv = 1.f / fmaxf(cnt[g], 1.f);
  float acc = 0.f;
  #pragma unroll
  for (int c = 0; c < HIDC; ++c)
    acc = fmaf(pooled[g * HIDC + c], w[c * NCLS + j], acc);
  out[t] = acc * inv + b[j];
}

extern "C" void kernel_launch(void* const* d_in, const int* in_sizes, int n_in,
                              void* d_out, int out_size, void* d_ws, size_t ws_size,
                              hipStream_t stream) {
  const float* x      = (const float*)d_in[0];
  const int*   ei     = (const int*)d_in[1];
  const int*   batch  = (const int*)d_in[2];
  const float* enc1_w = (const float*)d_in[3];
  const float* enc1_b = (const float*)d_in[4];
  const float* enc2_w = (const float*)d_in[5];
  const float* enc2_b = (const float*)d_in[6];
  const float* lin1_w = (const float*)d_in[7];
  const float* lin1_b = (const float*)d_in[8];
  const float* gw[4]  = {(const float*)d_in[9],  (const float*)d_in[13], (const float*)d_in[17], (const float*)d_in[21]};
  const float* gas[4] = {(const float*)d_in[10], (const float*)d_in[14], (const float*)d_in[18], (const float*)d_in[22]};
  const float* gad[4] = {(const float*)d_in[11], (const float*)d_in[15], (const float*)d_in[19], (const float*)d_in[23]};
  const float* gb[4]  = {(const float*)d_in[12], (const float*)d_in[16], (const float*)d_in[20], (const float*)d_in[24]};
  float* out = (float*)d_out;

  float* fws    = (float*)d_ws;
  float* hproj  = fws;
  float* hbig   = hproj  + (size_t)NNODES * 128;
  float* hsmall = hbig   + (size_t)NNODES * 256;
  float* scs    = hsmall + (size_t)NNODES * 32;
  float* scd    = scs    + (size_t)NNODES * 4;
  float* pooled = scd    + (size_t)NNODES * 4;
  float* cnt    = pooled + NGRAPH * HIDC;
  int*   deg    = (int*)(cnt + NGRAPH);
  int*   row_start = deg + NNODES;
  int*   col_src   = row_start + NNODES + 1;
  int*   bsum      = col_src + ETOT;
  int*   boff      = bsum + SCAN_BLOCKS;

  // --- CSR build (parallel scan) ---
  hipMemsetAsync(deg, 0, NNODES * sizeof(int), stream);
  hist_kernel<<<(ETOT + 255) / 256, 256, 0, stream>>>(ei, deg);
  scan_block_kernel<<<SCAN_BLOCKS, 256, 0, stream>>>(deg, row_start, bsum);
  scan_sums_kernel<<<1, 256, 0, stream>>>(bsum, boff);
  scan_add_kernel<<<SCAN_BLOCKS, 256, 0, stream>>>(boff, row_start);
  hipMemsetAsync(deg, 0, NNODES * sizeof(int), stream);
  scatter_kernel<<<(ETOT + 255) / 256, 256, 0, stream>>>(ei, row_start, deg, col_src);

  dim3 g128((NNODES + 63) / 64, 2), g256((NNODES + 63) / 64, 4);

  gemm_bias<<<g128, 256, 0, stream>>>(x,     enc1_w, enc1_b, hproj, NNODES, 128, 128);
  gemm_bias<<<g256, 256, 0, stream>>>(hproj, enc2_w, enc2_b, hbig,  NNODES, 128, 256);

  const float* cur = hbig; int curK = 256;
  for (int L = 0; L < 4; ++L) {
    gemm_bias<<<g128, 256, 0, stream>>>(cur, gw[L], nullptr, hproj, NNODES, curK, 128);
    scores_kernel<<<(NNODES + 3) / 4, 256, 0, stream>>>(hproj, gas[L], gad[L], scs, scd);
    gat_edge_kernel<<<(NNODES + 3) / 4, 256, 0, stream>>>(hproj, scs, scd, row_start, col_src, gb[L], hsmall);
    cur = hsmall; curK = 32;
  }

  hipMemsetAsync(pooled, 0, (NGRAPH * HIDC + NGRAPH) * sizeof(float), stream);
  pool_kernel<<<POOL_BLOCKS, 256, 0, stream>>>(hsmall, batch, pooled, cnt);
  final_kernel<<<1, 640, 0, stream>>>(pooled, cnt, lin1_w, lin1_b, out);
}